// Round 4
// baseline (201.268 us; speedup 1.0000x reference)
//
#include <hip/hip_runtime.h>
#include <hip/hip_bf16.h>

#define BATCH 2048
#define IDIM  256
#define ODIM  64
#define GRIDN 300

typedef __bf16 bf16x8 __attribute__((ext_vector_type(8)));
typedef float  f32x16 __attribute__((ext_vector_type(16)));
typedef unsigned int uint4v __attribute__((ext_vector_type(4)));

#define AS1 __attribute__((address_space(1)))
#define AS3 __attribute__((address_space(3)))

union ABFrag {
    unsigned short us[8];
    unsigned int   u32[4];
    uint4v         u4;
    bf16x8         bv;
};

__device__ __forceinline__ unsigned short f2bf(float f) {
    union { __hip_bfloat16 h; unsigned short u; } v;
    v.h = __float2bfloat16(f);   // RNE; pairs fuse into v_cvt_pk_bf16_f32
    return v.u;
}

// ---------------------------------------------------------------------------
// Prep: fouriercoeffs [2][64][256][300] f32 -> WP bf16 4KB chunks, one per
// (isplit ib, g). In-chunk byte = q*1024 + j*16 + (il&3)*4 + t*2, q = il>>2.
// Block = (gb, ib), gb covers 8 g's (last 4). Wave w = q, lane = j.
// Lane reads fc[t][j][ib*16+q*4+e][g0..g0+7], assembles dwords, writes 4KB
// chunks in LDS (b128, conflict-free), streams out fully coalesced.
// blk = gb*16 + ib: (ib,gb)/(ib,gb+1) share 64B source lines and land on the
// same XCD (16 % 8 == 0) -> L2 reuse of the half-line reads.
// ---------------------------------------------------------------------------
__global__ __launch_bounds__(256) void fkan_prep(const float* __restrict__ fc,
                                                 char* __restrict__ wp) {
    __shared__ alignas(16) char lds[32768];
    const int blk = blockIdx.x;
    const int ib  = blk & 15;          // i-split 0..15
    const int gb  = blk >> 4;          // 0..37
    const int g0  = gb * 8;
    const int G   = (gb == 37) ? 4 : 8;   // 300 = 37*8 + 4
    const int q   = threadIdx.x >> 6;     // wave = il quad
    const int j   = threadIdx.x & 63;     // lane = output col

    float vals[2][4][8];
    #pragma unroll
    for (int t = 0; t < 2; ++t) {
        #pragma unroll
        for (int e = 0; e < 4; ++e) {
            const float* src = fc + (((size_t)t * ODIM + j) * IDIM
                                     + (ib * 16 + q * 4 + e)) * GRIDN + g0;
            float4 lo = *(const float4*)(src);
            vals[t][e][0] = lo.x; vals[t][e][1] = lo.y;
            vals[t][e][2] = lo.z; vals[t][e][3] = lo.w;
            if (G == 8) {
                float4 hi = *(const float4*)(src + 4);
                vals[t][e][4] = hi.x; vals[t][e][5] = hi.y;
                vals[t][e][6] = hi.z; vals[t][e][7] = hi.w;
            }
        }
    }
    #pragma unroll
    for (int g = 0; g < 8; ++g) {
        if (g < 4 || G == 8) {
            uint4v dw;
            #pragma unroll
            for (int e = 0; e < 4; ++e)
                dw[e] = (unsigned)f2bf(vals[0][e][g]) | ((unsigned)f2bf(vals[1][e][g]) << 16);
            *(uint4v*)(lds + g * 4096 + q * 1024 + j * 16) = dw;
        }
    }
    __syncthreads();
    char* dst = wp + ((size_t)ib * GRIDN + g0) * 4096;
    for (int w = threadIdx.x * 16; w < G * 4096; w += 256 * 16)
        *(uint4v*)(dst + w) = *(const uint4v*)(lds + w);
}

// ---------------------------------------------------------------------------
// Main: grid 1024; xcd = bid&7, slice = xcd*8+((bid>>3)&7) -> (isplit, gq),
// mtile = bid>>6 (each XCD touches exactly 2 isplits -> 2.4MB, L2-fit).
// Block = 4 waves x (32 rows x 64 cols), shared B chunk per g.
// T3/T4 pipeline, RACE-FIXED ordering per iter it:
//   [s_waitcnt vmcnt(2)]  -- own chunk-it portion landed (2 newer in flight)
//   [s_barrier]           -- => ALL waves' chunk-it portions landed;
//                            ALL iter-(it-1) reads of slot (it-1)&3 sealed
//   [issue chunk it+3 -> slot (it+3)&3 == (it-1)&3]   -- now safe to overwrite
//   [ds_read slot it&3] [MFMA x4] [recurrence]
// (R3 issued the DMA BEFORE the barrier -> overwrote a slot still being read.)
// Tail: clamped dup loads keep vmcnt math uniform; dup target slots
// (3,0,1 at it=72,73,74) are never read again afterwards.
// T5: setprio(1) around the MFMA cluster.
// ---------------------------------------------------------------------------
__global__ __launch_bounds__(256, 4) void fkan_main(const float* __restrict__ x,
                                                    const char* __restrict__ wp,
                                                    float* __restrict__ out) {
    __shared__ alignas(16) char lds[16384];   // 4-deep ring of 4KB chunks

    const int bid    = blockIdx.x;
    const int xcd    = bid & 7;
    const int within = bid >> 3;                 // 0..127
    const int slice  = xcd * 8 + (within & 7);   // 0..63
    const int mtile  = within >> 3;              // 0..15
    const int isplit = slice >> 2;               // 0..15
    const int gq     = slice & 3;                // 0..3
    const int g_begin = gq * 75;

    const int tid  = threadIdx.x;
    const int wave = tid >> 6;
    const int lane = tid & 63;
    const int l31  = lane & 31;
    const int kgrp = lane >> 5;
    const int row  = mtile * 128 + wave * 32 + l31;   // batch row (A lane row)

    // --- init 8 recurrence states: ss = h*4+p  <->  il = h*8 + kgrp*4 + p ---
    float stc[8], sts[8], bcs[8], bss[8];
    const float* xrow = x + (size_t)row * IDIM + isplit * 16;
    #pragma unroll
    for (int h = 0; h < 2; ++h) {
        const float4 xv4 = *(const float4*)(xrow + h * 8 + kgrp * 4);
        float xa[4] = {xv4.x, xv4.y, xv4.z, xv4.w};
        #pragma unroll
        for (int p = 0; p < 4; ++p) {
            const int ss = h * 4 + p;
            const float xv = xa[p];
            float sb, cb;
            __sincosf(xv, &sb, &cb);
            bcs[ss] = cb; bss[ss] = sb;
            float s0 = sb, c0 = cb;
            if (g_begin != 0) __sincosf((float)(g_begin + 1) * xv, &s0, &c0);
            stc[ss] = c0; sts[ss] = s0;
        }
    }

    // B-frag read base: q*1024 + jcol*16;  q = kchunk*2 + kgrp
    const unsigned aq = (unsigned)kgrp * 1024 + (unsigned)l31 * 16;
    const char* wbase = wp + ((size_t)(isplit * GRIDN + g_begin)) * 4096 + tid * 16;

    // prologue: issue chunks 0,1,2 into ring slots 0,1,2 (3 outstanding)
    #pragma unroll
    for (int p = 0; p < 3; ++p)
        __builtin_amdgcn_global_load_lds((const AS1 unsigned int*)(wbase + (size_t)p * 4096),
                                         (AS3 unsigned int*)(lds + p * 4096 + tid * 16),
                                         16, 0, 0);

    f32x16 acc0 = {0,0,0,0,0,0,0,0,0,0,0,0,0,0,0,0};
    f32x16 acc1 = {0,0,0,0,0,0,0,0,0,0,0,0,0,0,0,0};

    #pragma unroll 2
    for (int it = 0; it < 75; ++it) {
        // own chunk-it portion landed (chunks it+1, it+2 still in flight)
        asm volatile("s_waitcnt vmcnt(2)" ::: "memory");
        __builtin_amdgcn_s_barrier();
        asm volatile("" ::: "memory");
        // NOW safe: slot (it+3)&3 == (it-1)&3, reads sealed by the barrier above
        const int nxt = (it + 3 <= 74) ? (it + 3) : 74;
        __builtin_amdgcn_global_load_lds(
            (const AS1 unsigned int*)(wbase + (size_t)nxt * 4096),
            (AS3 unsigned int*)(lds + ((it + 3) & 3) * 4096 + tid * 16),
            16, 0, 0);

        const char* base = lds + (it & 3) * 4096;
        ABFrag b00, b01, b10, b11, af1, af2;
        b00.u4 = *(const uint4v*)(base + aq);           // kchunk0, cols 0..31
        b01.u4 = *(const uint4v*)(base + aq + 512);     // kchunk0, cols 32..63
        b10.u4 = *(const uint4v*)(base + aq + 2048);    // kchunk1, cols 0..31
        b11.u4 = *(const uint4v*)(base + aq + 2560);    // kchunk1, cols 32..63
        #pragma unroll
        for (int p = 0; p < 4; ++p) {
            af1.us[2*p]   = f2bf(stc[p]);     // kl even = cos
            af1.us[2*p+1] = f2bf(sts[p]);     // kl odd  = sin
            af2.us[2*p]   = f2bf(stc[4+p]);
            af2.us[2*p+1] = f2bf(sts[4+p]);
        }
        __builtin_amdgcn_s_setprio(1);
        acc0 = __builtin_amdgcn_mfma_f32_32x32x16_bf16(af1.bv, b00.bv, acc0, 0, 0, 0);
        acc1 = __builtin_amdgcn_mfma_f32_32x32x16_bf16(af1.bv, b01.bv, acc1, 0, 0, 0);
        acc0 = __builtin_amdgcn_mfma_f32_32x32x16_bf16(af2.bv, b10.bv, acc0, 0, 0, 0);
        acc1 = __builtin_amdgcn_mfma_f32_32x32x16_bf16(af2.bv, b11.bv, acc1, 0, 0, 0);
        __builtin_amdgcn_s_setprio(0);
        // advance phases (angle addition; fp32, ~2e-4 rad drift over 75 steps)
        #pragma unroll
        for (int ss = 0; ss < 8; ++ss) {
            const float c = stc[ss], s = sts[ss];
            stc[ss] = c * bcs[ss] - s * bss[ss];
            sts[ss] = s * bcs[ss] + c * bss[ss];
        }
    }

    // epilogue: D layout (32x32): col=lane&31, row=(r&3)+8*(r>>2)+4*(lane>>5)
    #pragma unroll
    for (int r = 0; r < 16; ++r) {
        const int orow = mtile * 128 + wave * 32 + (r & 3) + 8 * (r >> 2) + 4 * kgrp;
        unsafeAtomicAdd(out + (size_t)orow * ODIM + l31, acc0[r]);
        unsafeAtomicAdd(out + (size_t)orow * ODIM + 32 + l31, acc1[r]);
    }
}

// ---------------------------------------------------------------------------
// Fallback (ws too small): exact fp32, one thread per (b,j). Slow but correct.
// ---------------------------------------------------------------------------
__global__ __launch_bounds__(256) void fkan_naive(const float* __restrict__ x,
                                                  const float* __restrict__ fc,
                                                  float* __restrict__ out) {
    const int j = blockIdx.x >> 3;
    const int b = (blockIdx.x & 7) * 256 + threadIdx.x;
    const float* xr = x + (size_t)b * IDIM;
    float acc = 0.f;
    for (int i = 0; i < IDIM; ++i) {
        const float xv = xr[i];
        float sb, cb;
        __sincosf(xv, &sb, &cb);
        float c = cb, s = sb;
        const float* wc = fc + ((size_t)j * IDIM + i) * GRIDN;
        const float* ws = wc + (size_t)ODIM * IDIM * GRIDN;
        for (int g = 0; g < GRIDN; ++g) {
            acc += c * wc[g] + s * ws[g];
            const float cn = c * cb - s * sb;
            s = s * cb + c * sb;
            c = cn;
        }
    }
    out[(size_t)b * ODIM + j] = acc;
}

extern "C" void kernel_launch(void* const* d_in, const int* in_sizes, int n_in,
                              void* d_out, int out_size, void* d_ws, size_t ws_size,
                              hipStream_t stream) {
    const float* x  = (const float*)d_in[0];
    const float* fc = (const float*)d_in[1];
    float* out = (float*)d_out;
    constexpr size_t WPB = 16ull * GRIDN * 4096;   // 19.66 MB bf16 weight image

    if (ws_size >= WPB) {
        hipMemsetAsync(d_out, 0, (size_t)out_size * sizeof(float), stream);
        fkan_prep<<<608, 256, 0, stream>>>(fc, (char*)d_ws);
        fkan_main<<<1024, 256, 0, stream>>>(x, (const char*)d_ws, out);
    } else {
        fkan_naive<<<512, 256, 0, stream>>>(x, fc, out);
    }
}